// Round 11
// baseline (149.991 us; speedup 1.0000x reference)
//
#include <hip/hip_runtime.h>
#include <math.h>

#define NB 256        // batch = grid
#define N 128         // DIMX = DIMY = DIMH
#define NTHREADS 512  // 8 waves: thread = (k<<2)|h, k=0..127 row, h=0..3 K-quarter
#define MAX_IT 500
// Chebyshev step cycling over [0.5, 1.8] (kept from r10: passed, small gain).
#define ALF0 0.57126f
#define ALF1 1.81991f
#define ALF2 0.71493f
#define ALF3 1.10956f
// LDS vectors: 4 slices of 32 floats, 40-float stride (bank-disjoint).
#define SLICE 40
#define SLOT(k) ((((k) >> 5) * SLICE) + ((k) & 31))
#define LDSVEC (3 * SLICE + 32)

// r10 calibration: T_iter ~2.2us but compute+barrier only ~1.0us. The gap is
// backward-weight L1 streaming: VGPR=128 can't hold the 96 backward floats,
// so the compiler re-gathers them from L1 EVERY iteration (96 scattered
// loads/thread ~ 196KB/iter/CU of L1 line traffic). Fix: S3's two backward
// matrices (wz1c, wy1 columns) become LDS IMAGES permuted into reader order:
//   img[i*512 + t] = the float4 thread t reads at chunk i
// -> one-time preamble writes and per-iter reads are both lane-consecutive
// float4s (conflict-free), values bit-identical to the register path.
// 2 x 64KB LDS; 1 block/CU anyway so the LDS bump costs nothing.

template <int CTRL>
__device__ __forceinline__ float dpp_add(float p) {
    return p + __int_as_float(__builtin_amdgcn_update_dpp(
                   0, __float_as_int(p), CTRL, 0xF, 0xF, true));
}
// quad (4-lane h-group) sum: bit-identical to shfl_xor(1)/shfl_xor(2).
__device__ __forceinline__ float quad_sum(float p) {
    p = dpp_add<0xB1>(p);
    p = dpp_add<0x4E>(p);
    return p;
}
__device__ __forceinline__ float wave_sum(float p) {
    p += __shfl_xor(p, 1);
    p += __shfl_xor(p, 2);
    p += __shfl_xor(p, 4);
    p += __shfl_xor(p, 8);
    p += __shfl_xor(p, 16);
    p += __shfl_xor(p, 32);
    return p;
}
__device__ __forceinline__ float softplus_f(float s) {
    float e = __expf(-fabsf(s));
    return fmaxf(s, 0.f) + __logf(1.f + e);
}
__device__ __forceinline__ float sigmoid_f(float s) {
    float e = __expf(-fabsf(s));
    float r = 1.f / (1.f + e);
    return s >= 0.f ? r : 1.f - r;
}

// row matvec for precompute: dot of W row k (global) with 128-vector V (LDS,
// slice-padded layout). Each lane sums its 32-slice, quad DPP-combine.
__device__ __forceinline__ float mv_row(const float* __restrict__ W,
                                        const float* __restrict__ V,
                                        int k, int h) {
    const float4* wr = (const float4*)(W + k * N + h * 32);
    const float4* vr = (const float4*)(V + h * SLICE);
    float q0 = 0.f, q1 = 0.f, q2 = 0.f, q3 = 0.f;
#pragma unroll
    for (int i = 0; i < 8; ++i) {
        float4 w = wr[i], v = vr[i];
        q0 = fmaf(w.x, v.x, q0); q1 = fmaf(w.y, v.y, q1);
        q2 = fmaf(w.z, v.z, q2); q3 = fmaf(w.w, v.w, q3);
    }
    return quad_sum((q0 + q1) + (q2 + q3));
}

__global__ __launch_bounds__(NTHREADS, 2)
void picnn_solve(const float* __restrict__ x, const float* __restrict__ y,
                 const float* __restrict__ wuu0_w, const float* __restrict__ wuu0_b,
                 const float* __restrict__ wyu0_w, const float* __restrict__ wyu0_b,
                 const float* __restrict__ wy0,
                 const float* __restrict__ wu0_w, const float* __restrict__ wu0_b,
                 const float* __restrict__ wuu1_w, const float* __restrict__ wuu1_b,
                 const float* __restrict__ wzu1_w, const float* __restrict__ wzu1_b,
                 const float* __restrict__ wz1,
                 const float* __restrict__ wyu1_w, const float* __restrict__ wyu1_b,
                 const float* __restrict__ wy1,
                 const float* __restrict__ wu1_w, const float* __restrict__ wu1_b,
                 const float* __restrict__ wzu2_w, const float* __restrict__ wzu2_b,
                 const float* __restrict__ wz2,
                 const float* __restrict__ wyu2_w, const float* __restrict__ wyu2_b,
                 const float* __restrict__ wy2,
                 float* __restrict__ out)
{
    const int b = blockIdx.x;
    const int t = threadIdx.x;
    const int k = t >> 2;   // output row 0..127
    const int h = t & 3;    // K-quarter 0..3
    const int wave = t >> 6;
    const int lane = t & 63;

    __shared__ __align__(16) float xv[LDSVEC];
    __shared__ __align__(16) float u0v[LDSVEC];
    __shared__ __align__(16) float u1v[LDSVEC];
    __shared__ __align__(16) float t0s[LDSVEC];
    __shared__ __align__(16) float t2s[LDSVEC];
    __shared__ __align__(16) float t1s[LDSVEC];
    __shared__ __align__(16) float d2s[LDSVEC];
    __shared__ __align__(16) float d1s[LDSVEC];
    __shared__ float rp[8];
    // backward-weight LDS images in reader order (64 KB each):
    __shared__ __align__(16) float4 img1[8 * NTHREADS];  // clip(wz1) cols
    __shared__ __align__(16) float4 img2[8 * NTHREADS];  // wy1 cols

    if (t < N) xv[SLOT(t)] = x[b * N + t];
    __syncthreads();

    // ---- per-sample iteration-invariant precompute ----
    float u0k = softplus_f(mv_row(wuu0_w, xv, k, h) + wuu0_b[k]);
    float a0  = mv_row(wyu0_w, xv, k, h) + wyu0_b[k];
    float c0  = mv_row(wu0_w,  xv, k, h) + wu0_b[k];
    if (h == 0) u0v[SLOT(k)] = u0k;
    __syncthreads();

    float u1k = softplus_f(mv_row(wuu1_w, u0v, k, h) + wuu1_b[k]);
    float zu  = softplus_f(mv_row(wzu1_w, u0v, k, h) + wzu1_b[k]);
    float a1  = mv_row(wyu1_w, u0v, k, h) + wyu1_b[k];
    float c1  = mv_row(wu1_w,  u0v, k, h) + wu1_b[k];
    if (h == 0) u1v[SLOT(k)] = u1k;
    __syncthreads();

    float a2 = mv_row(wyu2_w, u1v, k, h) + wyu2_b[k];
    float e2 = a2 * wy2[k];
    float dp;
    {
        // zu2 = sp(<wzu2_w, u1>): every quad computes the same full dot
        const float4* wr = (const float4*)(wzu2_w + h * 32);
        const float4* vr = (const float4*)(u1v + h * SLICE);
        float q0 = 0.f, q1 = 0.f, q2 = 0.f, q3 = 0.f;
#pragma unroll
        for (int i = 0; i < 8; ++i) {
            float4 w = wr[i], v = vr[i];
            q0 = fmaf(w.x, v.x, q0); q1 = fmaf(w.y, v.y, q1);
            q2 = fmaf(w.z, v.z, q2); q3 = fmaf(w.w, v.w, q3);
        }
        float zu2 = softplus_f(quad_sum((q0 + q1) + (q2 + q3)) + wzu2_b[0]);
        dp = zu2 * fmaxf(wz2[k], 0.f);
    }

    // ---- forward rows in registers; S4 backward cols left to the compiler;
    //      S3 backward cols gathered ONCE into LDS images ----
    float4 wf0[8], wf1[8], wf2[8];  // wy0 / clip(wz1) / wy1, row k, quarter h
    float4 wb0[8];                  // wy0 column k, row-quarter h (S4)
    {
        const float4* r0 = (const float4*)(wy0 + k * N + h * 32);
        const float4* r1 = (const float4*)(wz1 + k * N + h * 32);
        const float4* r2 = (const float4*)(wy1 + k * N + h * 32);
#pragma unroll
        for (int i = 0; i < 8; ++i) {
            wf0[i] = r0[i];
            float4 z = r1[i];
            z.x = fmaxf(z.x, 0.f); z.y = fmaxf(z.y, 0.f);
            z.z = fmaxf(z.z, 0.f); z.w = fmaxf(z.w, 0.f);
            wf1[i] = z;
            wf2[i] = r2[i];
        }
#pragma unroll
        for (int i = 0; i < 8; ++i) {
            int r = h * 32 + 4 * i;
            wb0[i].x = wy0[(r + 0) * N + k]; wb0[i].y = wy0[(r + 1) * N + k];
            wb0[i].z = wy0[(r + 2) * N + k]; wb0[i].w = wy0[(r + 3) * N + k];
            // S3 backward weights -> LDS images (reader-ordered, one-time):
            float4 z1c, c1c;
            z1c.x = fmaxf(wz1[(r + 0) * N + k], 0.f);
            z1c.y = fmaxf(wz1[(r + 1) * N + k], 0.f);
            z1c.z = fmaxf(wz1[(r + 2) * N + k], 0.f);
            z1c.w = fmaxf(wz1[(r + 3) * N + k], 0.f);
            img1[i * NTHREADS + t] = z1c;
            c1c.x = wy1[(r + 0) * N + k]; c1c.y = wy1[(r + 1) * N + k];
            c1c.z = wy1[(r + 2) * N + k]; c1c.w = wy1[(r + 3) * N + k];
            img2[i * NTHREADS + t] = c1c;
        }
    }

    const float yk = y[b * N + k];
    // Initial guess zeroing the linear part of the residual:
    //   g = 0.5*y1 + e2 + (small NN backprop terms)  ->  y1_0 = 2*(y - e2)
    float y1v = 2.f * (yk - e2);
    if (h == 0) { t0s[SLOT(k)] = y1v * a0; t2s[SLOT(k)] = y1v * a1; }
    __syncthreads();   // also publishes img1/img2

    // Chebyshev-cycled iteration y1 += alpha_it*(y - g(y1)) with early break.
    for (int it = 1; it <= MAX_IT; ++it) {
        // S1: s1 = t0@wy0^T + c0 ; s2a = t2@wy1^T  (fused pass over t0,t2)
        const float4* t0r = (const float4*)(t0s + h * SLICE);
        const float4* t2r = (const float4*)(t2s + h * SLICE);
        float p0 = 0.f, p1 = 0.f, p2 = 0.f, p3 = 0.f;
        float q0 = 0.f, q1 = 0.f, q2 = 0.f, q3 = 0.f;
#pragma unroll
        for (int i = 0; i < 8; ++i) {
            float4 v0 = t0r[i], v2 = t2r[i];
            p0 = fmaf(wf0[i].x, v0.x, p0); p1 = fmaf(wf0[i].y, v0.y, p1);
            p2 = fmaf(wf0[i].z, v0.z, p2); p3 = fmaf(wf0[i].w, v0.w, p3);
            q0 = fmaf(wf2[i].x, v2.x, q0); q1 = fmaf(wf2[i].y, v2.y, q1);
            q2 = fmaf(wf2[i].z, v2.z, q2); q3 = fmaf(wf2[i].w, v2.w, q3);
        }
        float s1  = quad_sum((p0 + p1) + (p2 + p3)) + c0;
        float s2a = quad_sum((q0 + q1) + (q2 + q3));
        float e1 = __expf(-fabsf(s1));
        float z1 = fmaxf(s1, 0.f) + __logf(1.f + e1);
        float rr1 = 1.f / (1.f + e1);
        float sig1 = (s1 >= 0.f) ? rr1 : 1.f - rr1;
        if (h == 0) t1s[SLOT(k)] = z1 * zu;
        __syncthreads();

        // S2: s2 = t1@wz1c^T + s2a + c1 ; d2 = dp*sigma(s2)
        const float4* t1r = (const float4*)(t1s + h * SLICE);
        p0 = p1 = p2 = p3 = 0.f;
#pragma unroll
        for (int i = 0; i < 8; ++i) {
            float4 v1 = t1r[i];
            p0 = fmaf(wf1[i].x, v1.x, p0); p1 = fmaf(wf1[i].y, v1.y, p1);
            p2 = fmaf(wf1[i].z, v1.z, p2); p3 = fmaf(wf1[i].w, v1.w, p3);
        }
        float s2 = quad_sum((p0 + p1) + (p2 + p3)) + s2a + c1;
        float d2 = dp * sigmoid_f(s2);
        if (h == 0) d2s[SLOT(k)] = d2;
        __syncthreads();

        // S3: q = d2@wz1c (cols) ; gc = d2@wy1 (cols) ; d1 = q*zu*sig1
        // backward weights now from the LDS images (lane-consecutive float4).
        const float4* d2r = (const float4*)(d2s + h * SLICE);
        p0 = p1 = p2 = p3 = 0.f; q0 = q1 = q2 = q3 = 0.f;
#pragma unroll
        for (int i = 0; i < 8; ++i) {
            float4 d = d2r[i];
            float4 w1 = img1[i * NTHREADS + t];
            float4 w2 = img2[i * NTHREADS + t];
            p0 = fmaf(w1.x, d.x, p0); p1 = fmaf(w1.y, d.y, p1);
            p2 = fmaf(w1.z, d.z, p2); p3 = fmaf(w1.w, d.w, p3);
            q0 = fmaf(w2.x, d.x, q0); q1 = fmaf(w2.y, d.y, q1);
            q2 = fmaf(w2.z, d.z, q2); q3 = fmaf(w2.w, d.w, q3);
        }
        float qv = quad_sum((p0 + p1) + (p2 + p3));
        float gc = quad_sum((q0 + q1) + (q2 + q3));
        float d1 = qv * zu * sig1;
        if (h == 0) d1s[SLOT(k)] = d1;
        __syncthreads();

        // S4: gb = d1@wy0 (cols); g; Chebyshev-step update; residual reduce
        const float4* d1r = (const float4*)(d1s + h * SLICE);
        p0 = p1 = p2 = p3 = 0.f;
#pragma unroll
        for (int i = 0; i < 8; ++i) {
            float4 d = d1r[i];
            p0 = fmaf(wb0[i].x, d.x, p0); p1 = fmaf(wb0[i].y, d.y, p1);
            p2 = fmaf(wb0[i].z, d.z, p2); p3 = fmaf(wb0[i].w, d.w, p3);
        }
        float gb = quad_sum((p0 + p1) + (p2 + p3));
        float g = fmaf(0.5f, y1v, e2) + gc * a1 + gb * a0;
        float rres = yk - g;
        int ph = (it - 1) & 3;
        float alf = (ph == 0) ? ALF0 : (ph == 1) ? ALF1
                  : (ph == 2) ? ALF2 : ALF3;
        y1v = fmaf(alf, rres, y1v);
        if (h == 0) { t0s[SLOT(k)] = y1v * a0; t2s[SLOT(k)] = y1v * a1; }
        float rs = wave_sum(rres * rres);   // = 4 * sum over this wave's 16 k's
        if (lane == 0) rp[wave] = rs;
        __syncthreads();
        float tot = ((rp[0] + rp[1]) + (rp[2] + rp[3]))
                  + ((rp[4] + rp[5]) + (rp[6] + rp[7]));  // = 4*||r||^2
        if (tot < 4e-6f) break;  // per-sample ||r|| < 1e-3 (update already applied)
    }

    // out[b] = mean_k(y1 + y)
    __syncthreads();
    float v = wave_sum(y1v + yk);           // 4x duplicated per k
    if (lane == 0) rp[wave] = v;
    __syncthreads();
    if (t == 0) {
        float s = ((rp[0] + rp[1]) + (rp[2] + rp[3]))
                + ((rp[4] + rp[5]) + (rp[6] + rp[7]));
        out[b] = s * (1.f / 512.f);         // /4 duplication /128 mean
    }
}

extern "C" void kernel_launch(void* const* d_in, const int* in_sizes, int n_in,
                              void* d_out, int out_size, void* d_ws, size_t ws_size,
                              hipStream_t stream) {
    const float* x      = (const float*)d_in[0];
    const float* y      = (const float*)d_in[1];
    const float* wuu0_w = (const float*)d_in[2];
    const float* wuu0_b = (const float*)d_in[3];
    const float* wyu0_w = (const float*)d_in[4];
    const float* wyu0_b = (const float*)d_in[5];
    const float* wy0    = (const float*)d_in[6];
    const float* wu0_w  = (const float*)d_in[7];
    const float* wu0_b  = (const float*)d_in[8];
    const float* wuu1_w = (const float*)d_in[9];
    const float* wuu1_b = (const float*)d_in[10];
    const float* wzu1_w = (const float*)d_in[11];
    const float* wzu1_b = (const float*)d_in[12];
    const float* wz1    = (const float*)d_in[13];
    const float* wyu1_w = (const float*)d_in[14];
    const float* wyu1_b = (const float*)d_in[15];
    const float* wy1    = (const float*)d_in[16];
    const float* wu1_w  = (const float*)d_in[17];
    const float* wu1_b  = (const float*)d_in[18];
    const float* wzu2_w = (const float*)d_in[19];
    const float* wzu2_b = (const float*)d_in[20];
    const float* wz2    = (const float*)d_in[21];
    const float* wyu2_w = (const float*)d_in[22];
    const float* wyu2_b = (const float*)d_in[23];
    const float* wy2    = (const float*)d_in[24];
    // d_in[25]/[26] (wu2_w, wu2_b) shift the value, not the gradient -> unused
    float* out = (float*)d_out;

    picnn_solve<<<dim3(NB), dim3(NTHREADS), 0, stream>>>(
        x, y, wuu0_w, wuu0_b, wyu0_w, wyu0_b, wy0, wu0_w, wu0_b,
        wuu1_w, wuu1_b, wzu1_w, wzu1_b, wz1, wyu1_w, wyu1_b, wy1, wu1_w, wu1_b,
        wzu2_w, wzu2_b, wz2, wyu2_w, wyu2_b, wy2, out);
}

// Round 12
// 145.323 us; speedup vs baseline: 1.0321x; 1.0321x over previous
//
#include <hip/hip_runtime.h>
#include <math.h>

#define NB 256        // batch = grid
#define N 128         // DIMX = DIMY = DIMH
#define NTHREADS 512  // 8 waves: thread = (k<<2)|h, k=0..127 row, h=0..3 K-quarter
#define MAX_IT 500
// Chebyshev step cycling over [0.5, 1.8] (r10: passed, small gain).
#define ALF0 0.57126f
#define ALF1 1.81991f
#define ALF2 0.71493f
#define ALF3 1.10956f
// LDS vectors: 4 slices of 32 floats, 40-float stride (bank-disjoint).
#define SLICE 40
#define SLOT(k) ((((k) >> 5) * SLICE) + ((k) & 31))
#define LDSVEC (3 * SLICE + 32)

// r11 model: ~5300cy/iter = ~770 FMA issue + 4x(LDS rt + barrier) + trans +
// ~500-800cy of end-of-iter check machinery (6-deep shfl_xor chain + rp
// round-trip + branch, serialized before S1). This round cuts: (1) S1 reads
// ONE vector (a0/a1 folded into weights, numerics proven r1/r5), (2) residual
// reduce = DPP row_sum16 (proven r6) + 2 shfl_xor instead of 6, (3) check
// deferred to top of next iteration, hidden under the y1 loads (identical
// break iteration and output; rp/y1s races excluded by >=3 barriers between
// producer and consumer, epilogue barrier protects rp reuse).

template <int CTRL>
__device__ __forceinline__ float dpp_add(float p) {
    return p + __int_as_float(__builtin_amdgcn_update_dpp(
                   0, __float_as_int(p), CTRL, 0xF, 0xF, true));
}
// quad (4-lane h-group) sum: bit-identical to shfl_xor(1)/shfl_xor(2).
__device__ __forceinline__ float quad_sum(float p) {
    p = dpp_add<0xB1>(p);
    p = dpp_add<0x4E>(p);
    return p;
}
// 16-lane-row total in every lane: quad + row_ror:4 (0x124) + row_ror:8
// (0x128). Proven on-device (r6 epilogue).
__device__ __forceinline__ float row_sum16(float p) {
    p = quad_sum(p);
    p = dpp_add<0x124>(p);
    p = dpp_add<0x128>(p);
    return p;
}
__device__ __forceinline__ float wave_sum(float p) {
    p += __shfl_xor(p, 1);
    p += __shfl_xor(p, 2);
    p += __shfl_xor(p, 4);
    p += __shfl_xor(p, 8);
    p += __shfl_xor(p, 16);
    p += __shfl_xor(p, 32);
    return p;
}
__device__ __forceinline__ float softplus_f(float s) {
    float e = __expf(-fabsf(s));
    return fmaxf(s, 0.f) + __logf(1.f + e);
}
__device__ __forceinline__ float sigmoid_f(float s) {
    float e = __expf(-fabsf(s));
    float r = 1.f / (1.f + e);
    return s >= 0.f ? r : 1.f - r;
}

// row matvec for precompute: dot of W row k (global) with 128-vector V (LDS,
// slice-padded layout). Each lane sums its 32-slice, quad DPP-combine.
__device__ __forceinline__ float mv_row(const float* __restrict__ W,
                                        const float* __restrict__ V,
                                        int k, int h) {
    const float4* wr = (const float4*)(W + k * N + h * 32);
    const float4* vr = (const float4*)(V + h * SLICE);
    float q0 = 0.f, q1 = 0.f, q2 = 0.f, q3 = 0.f;
#pragma unroll
    for (int i = 0; i < 8; ++i) {
        float4 w = wr[i], v = vr[i];
        q0 = fmaf(w.x, v.x, q0); q1 = fmaf(w.y, v.y, q1);
        q2 = fmaf(w.z, v.z, q2); q3 = fmaf(w.w, v.w, q3);
    }
    return quad_sum((q0 + q1) + (q2 + q3));
}

__global__ __launch_bounds__(NTHREADS, 2)
void picnn_solve(const float* __restrict__ x, const float* __restrict__ y,
                 const float* __restrict__ wuu0_w, const float* __restrict__ wuu0_b,
                 const float* __restrict__ wyu0_w, const float* __restrict__ wyu0_b,
                 const float* __restrict__ wy0,
                 const float* __restrict__ wu0_w, const float* __restrict__ wu0_b,
                 const float* __restrict__ wuu1_w, const float* __restrict__ wuu1_b,
                 const float* __restrict__ wzu1_w, const float* __restrict__ wzu1_b,
                 const float* __restrict__ wz1,
                 const float* __restrict__ wyu1_w, const float* __restrict__ wyu1_b,
                 const float* __restrict__ wy1,
                 const float* __restrict__ wu1_w, const float* __restrict__ wu1_b,
                 const float* __restrict__ wzu2_w, const float* __restrict__ wzu2_b,
                 const float* __restrict__ wz2,
                 const float* __restrict__ wyu2_w, const float* __restrict__ wyu2_b,
                 const float* __restrict__ wy2,
                 float* __restrict__ out)
{
    const int b = blockIdx.x;
    const int t = threadIdx.x;
    const int k = t >> 2;   // output row 0..127
    const int h = t & 3;    // K-quarter 0..3
    const int wave = t >> 6;
    const int lane = t & 63;

    __shared__ __align__(16) float xv[LDSVEC];
    __shared__ __align__(16) float u0v[LDSVEC];
    __shared__ __align__(16) float u1v[LDSVEC];
    __shared__ __align__(16) float a0s[LDSVEC];
    __shared__ __align__(16) float a1s[LDSVEC];
    __shared__ __align__(16) float y1s[LDSVEC];
    __shared__ __align__(16) float t1s[LDSVEC];
    __shared__ __align__(16) float d2s[LDSVEC];
    __shared__ __align__(16) float d1s[LDSVEC];
    __shared__ float rp[8];
    // backward-weight LDS images in reader order (64 KB each):
    __shared__ __align__(16) float4 img1[8 * NTHREADS];  // clip(wz1) cols
    __shared__ __align__(16) float4 img2[8 * NTHREADS];  // wy1 cols * a1k

    if (t < N) xv[SLOT(t)] = x[b * N + t];
    __syncthreads();

    // ---- per-sample iteration-invariant precompute ----
    float u0k = softplus_f(mv_row(wuu0_w, xv, k, h) + wuu0_b[k]);
    float a0k = mv_row(wyu0_w, xv, k, h) + wyu0_b[k];
    float c0  = mv_row(wu0_w,  xv, k, h) + wu0_b[k];
    if (h == 0) { u0v[SLOT(k)] = u0k; a0s[SLOT(k)] = a0k; }
    __syncthreads();

    float u1k = softplus_f(mv_row(wuu1_w, u0v, k, h) + wuu1_b[k]);
    float zu  = softplus_f(mv_row(wzu1_w, u0v, k, h) + wzu1_b[k]);
    float a1k = mv_row(wyu1_w, u0v, k, h) + wyu1_b[k];
    float c1  = mv_row(wu1_w,  u0v, k, h) + wu1_b[k];
    if (h == 0) { u1v[SLOT(k)] = u1k; a1s[SLOT(k)] = a1k; }
    __syncthreads();

    float a2 = mv_row(wyu2_w, u1v, k, h) + wyu2_b[k];
    float dp;
    {
        // zu2 = sp(<wzu2_w, u1>): every quad computes the same full dot
        const float4* wr = (const float4*)(wzu2_w + h * 32);
        const float4* vr = (const float4*)(u1v + h * SLICE);
        float q0 = 0.f, q1 = 0.f, q2 = 0.f, q3 = 0.f;
#pragma unroll
        for (int i = 0; i < 8; ++i) {
            float4 w = wr[i], v = vr[i];
            q0 = fmaf(w.x, v.x, q0); q1 = fmaf(w.y, v.y, q1);
            q2 = fmaf(w.z, v.z, q2); q3 = fmaf(w.w, v.w, q3);
        }
        float zu2 = softplus_f(quad_sum((q0 + q1) + (q2 + q3)) + wzu2_b[0]);
        dp = zu2 * fmaxf(wz2[k], 0.f);
    }

    // ---- weights: forward rows (a0/a1 folded in), S4 col (a0k folded),
    //      S3 cols in LDS images (a1k folded into img2) ----
    float4 wf0[8], wf1[8], wf2[8];  // wy0*diag(a0) / clip(wz1) / wy1*diag(a1)
    float4 wb0[8];                  // wy0 column k * a0k
    {
        const float4* r0 = (const float4*)(wy0 + k * N + h * 32);
        const float4* r1 = (const float4*)(wz1 + k * N + h * 32);
        const float4* r2 = (const float4*)(wy1 + k * N + h * 32);
        const float4* a0r = (const float4*)(a0s + h * SLICE);
        const float4* a1r = (const float4*)(a1s + h * SLICE);
#pragma unroll
        for (int i = 0; i < 8; ++i) {
            float4 a = r0[i], s0 = a0r[i];
            a.x *= s0.x; a.y *= s0.y; a.z *= s0.z; a.w *= s0.w;
            wf0[i] = a;
            float4 z = r1[i];
            z.x = fmaxf(z.x, 0.f); z.y = fmaxf(z.y, 0.f);
            z.z = fmaxf(z.z, 0.f); z.w = fmaxf(z.w, 0.f);
            wf1[i] = z;
            float4 c = r2[i], s1 = a1r[i];
            c.x *= s1.x; c.y *= s1.y; c.z *= s1.z; c.w *= s1.w;
            wf2[i] = c;
        }
#pragma unroll
        for (int i = 0; i < 8; ++i) {
            int r = h * 32 + 4 * i;
            wb0[i].x = wy0[(r + 0) * N + k] * a0k;
            wb0[i].y = wy0[(r + 1) * N + k] * a0k;
            wb0[i].z = wy0[(r + 2) * N + k] * a0k;
            wb0[i].w = wy0[(r + 3) * N + k] * a0k;
            float4 z1c, c1c;
            z1c.x = fmaxf(wz1[(r + 0) * N + k], 0.f);
            z1c.y = fmaxf(wz1[(r + 1) * N + k], 0.f);
            z1c.z = fmaxf(wz1[(r + 2) * N + k], 0.f);
            z1c.w = fmaxf(wz1[(r + 3) * N + k], 0.f);
            img1[i * NTHREADS + t] = z1c;
            c1c.x = wy1[(r + 0) * N + k] * a1k;
            c1c.y = wy1[(r + 1) * N + k] * a1k;
            c1c.z = wy1[(r + 2) * N + k] * a1k;
            c1c.w = wy1[(r + 3) * N + k] * a1k;
            img2[i * NTHREADS + t] = c1c;
        }
    }

    const float yk = y[b * N + k];
    const float ye2 = yk - a2 * wy2[k];   // yk - e2
    // Initial guess zeroing the linear part of the residual:
    //   g = 0.5*y1 + e2 + (small NN backprop terms)  ->  y1_0 = 2*(yk - e2)
    float y1v = 2.f * ye2;
    if (h == 0) y1s[SLOT(k)] = y1v;
    __syncthreads();   // also publishes img1/img2

    // Chebyshev-cycled iteration, deferred convergence check (prev-iter rp
    // read at top, hidden under the y1 slice loads; break iteration and
    // output identical to the end-of-iteration check).
    for (int it = 1; it <= MAX_IT; ++it) {
        // S1: issue y1 loads first, then resolve prev-iter convergence
        const float4* yr = (const float4*)(y1s + h * SLICE);
        float4 vv[8];
#pragma unroll
        for (int i = 0; i < 8; ++i) vv[i] = yr[i];
        if (it > 1) {
            const float4* rpv = (const float4*)rp;
            float4 ua = rpv[0], ub = rpv[1];
            float4 u = ua + ub;                 // = 4*||r||^2 (prev iter)
            float tot = (u.x + u.y) + (u.z + u.w);
            if (tot < 4e-6f) break;  // ||r|| < 1e-3 (update already applied)
        }
        // s1 = (wy0 diag(a0)) y1 + c0 ; s2a = (wy1 diag(a1)) y1
        float p0 = 0.f, p1 = 0.f, p2 = 0.f, p3 = 0.f;
        float q0 = 0.f, q1 = 0.f, q2 = 0.f, q3 = 0.f;
#pragma unroll
        for (int i = 0; i < 8; ++i) {
            float4 v = vv[i];
            p0 = fmaf(wf0[i].x, v.x, p0); p1 = fmaf(wf0[i].y, v.y, p1);
            p2 = fmaf(wf0[i].z, v.z, p2); p3 = fmaf(wf0[i].w, v.w, p3);
            q0 = fmaf(wf2[i].x, v.x, q0); q1 = fmaf(wf2[i].y, v.y, q1);
            q2 = fmaf(wf2[i].z, v.z, q2); q3 = fmaf(wf2[i].w, v.w, q3);
        }
        float s1  = quad_sum((p0 + p1) + (p2 + p3)) + c0;
        float s2a = quad_sum((q0 + q1) + (q2 + q3));
        float e1 = __expf(-fabsf(s1));
        float z1 = fmaxf(s1, 0.f) + __logf(1.f + e1);
        float rr1 = 1.f / (1.f + e1);
        float sig1 = (s1 >= 0.f) ? rr1 : 1.f - rr1;
        if (h == 0) t1s[SLOT(k)] = z1 * zu;
        __syncthreads();

        // S2: s2 = t1@wz1c^T + s2a + c1 ; d2 = dp*sigma(s2)
        const float4* t1r = (const float4*)(t1s + h * SLICE);
        p0 = p1 = p2 = p3 = 0.f;
#pragma unroll
        for (int i = 0; i < 8; ++i) {
            float4 v1 = t1r[i];
            p0 = fmaf(wf1[i].x, v1.x, p0); p1 = fmaf(wf1[i].y, v1.y, p1);
            p2 = fmaf(wf1[i].z, v1.z, p2); p3 = fmaf(wf1[i].w, v1.w, p3);
        }
        float s2 = quad_sum((p0 + p1) + (p2 + p3)) + s2a + c1;
        float d2 = dp * sigmoid_f(s2);
        if (h == 0) d2s[SLOT(k)] = d2;
        __syncthreads();

        // S3: q = d2@wz1c (cols, img1) ; gc' = d2@(wy1 col * a1k) (img2)
        const float4* d2r = (const float4*)(d2s + h * SLICE);
        p0 = p1 = p2 = p3 = 0.f; q0 = q1 = q2 = q3 = 0.f;
#pragma unroll
        for (int i = 0; i < 8; ++i) {
            float4 d = d2r[i];
            float4 w1 = img1[i * NTHREADS + t];
            float4 w2 = img2[i * NTHREADS + t];
            p0 = fmaf(w1.x, d.x, p0); p1 = fmaf(w1.y, d.y, p1);
            p2 = fmaf(w1.z, d.z, p2); p3 = fmaf(w1.w, d.w, p3);
            q0 = fmaf(w2.x, d.x, q0); q1 = fmaf(w2.y, d.y, q1);
            q2 = fmaf(w2.z, d.z, q2); q3 = fmaf(w2.w, d.w, q3);
        }
        float qv  = quad_sum((p0 + p1) + (p2 + p3));
        float gcp = quad_sum((q0 + q1) + (q2 + q3));   // = gc * a1k
        float d1 = qv * zu * sig1;
        if (h == 0) d1s[SLOT(k)] = d1;
        __syncthreads();

        // S4: gb' = d1@(wy0 col * a0k); update; cheap residual reduce
        const float4* d1r = (const float4*)(d1s + h * SLICE);
        p0 = p1 = p2 = p3 = 0.f;
#pragma unroll
        for (int i = 0; i < 8; ++i) {
            float4 d = d1r[i];
            p0 = fmaf(wb0[i].x, d.x, p0); p1 = fmaf(wb0[i].y, d.y, p1);
            p2 = fmaf(wb0[i].z, d.z, p2); p3 = fmaf(wb0[i].w, d.w, p3);
        }
        float gbp = quad_sum((p0 + p1) + (p2 + p3));   // = gb * a0k
        float rres = ye2 - fmaf(0.5f, y1v, gcp + gbp);
        int ph = (it - 1) & 3;
        float alf = (ph == 0) ? ALF0 : (ph == 1) ? ALF1
                  : (ph == 2) ? ALF2 : ALF3;
        y1v = fmaf(alf, rres, y1v);
        if (h == 0) y1s[SLOT(k)] = y1v;
        // residual: DPP row tree + 2 shfl (was 6) -> rp[wave] = 4*sum(16 k's)
        float rs = row_sum16(rres * rres);
        rs += __shfl_xor(rs, 16);
        rs += __shfl_xor(rs, 32);
        if (lane == 0) rp[wave] = rs;
        __syncthreads();
    }

    // out[b] = mean_k(y1 + y)
    __syncthreads();   // all waves done reading rp at loop top
    float v = wave_sum(y1v + yk);           // 4x duplicated per k
    if (lane == 0) rp[wave] = v;
    __syncthreads();
    if (t == 0) {
        float s = ((rp[0] + rp[1]) + (rp[2] + rp[3]))
                + ((rp[4] + rp[5]) + (rp[6] + rp[7]));
        out[b] = s * (1.f / 512.f);         // /4 duplication /128 mean
    }
}

extern "C" void kernel_launch(void* const* d_in, const int* in_sizes, int n_in,
                              void* d_out, int out_size, void* d_ws, size_t ws_size,
                              hipStream_t stream) {
    const float* x      = (const float*)d_in[0];
    const float* y      = (const float*)d_in[1];
    const float* wuu0_w = (const float*)d_in[2];
    const float* wuu0_b = (const float*)d_in[3];
    const float* wyu0_w = (const float*)d_in[4];
    const float* wyu0_b = (const float*)d_in[5];
    const float* wy0    = (const float*)d_in[6];
    const float* wu0_w  = (const float*)d_in[7];
    const float* wu0_b  = (const float*)d_in[8];
    const float* wuu1_w = (const float*)d_in[9];
    const float* wuu1_b = (const float*)d_in[10];
    const float* wzu1_w = (const float*)d_in[11];
    const float* wzu1_b = (const float*)d_in[12];
    const float* wz1    = (const float*)d_in[13];
    const float* wyu1_w = (const float*)d_in[14];
    const float* wyu1_b = (const float*)d_in[15];
    const float* wy1    = (const float*)d_in[16];
    const float* wu1_w  = (const float*)d_in[17];
    const float* wu1_b  = (const float*)d_in[18];
    const float* wzu2_w = (const float*)d_in[19];
    const float* wzu2_b = (const float*)d_in[20];
    const float* wz2    = (const float*)d_in[21];
    const float* wyu2_w = (const float*)d_in[22];
    const float* wyu2_b = (const float*)d_in[23];
    const float* wy2    = (const float*)d_in[24];
    // d_in[25]/[26] (wu2_w, wu2_b) shift the value, not the gradient -> unused
    float* out = (float*)d_out;

    picnn_solve<<<dim3(NB), dim3(NTHREADS), 0, stream>>>(
        x, y, wuu0_w, wuu0_b, wyu0_w, wyu0_b, wy0, wu0_w, wu0_b,
        wuu1_w, wuu1_b, wzu1_w, wzu1_b, wz1, wyu1_w, wyu1_b, wy1, wu1_w, wu1_b,
        wzu2_w, wzu2_b, wz2, wyu2_w, wyu2_b, wy2, out);
}